// Round 7
// baseline (335.780 us; speedup 1.0000x reference)
//
#include <hip/hip_runtime.h>
#include <cstddef>
#include <cstdint>

typedef __bf16 bf16;
typedef __bf16 bf16x4 __attribute__((ext_vector_type(4)));
typedef __bf16 bf16x8 __attribute__((ext_vector_type(8)));
typedef float f32x4 __attribute__((ext_vector_type(4)));

#define AS1C(p) ((const __attribute__((address_space(1))) void*)(p))
#define AS3(p)  ((__attribute__((address_space(3))) void*)(p))

#define MROWS 16384
#define HDIM 2560
#define EDIM 1024
#define LSEQ 4096

static __device__ const int kHeadOff[8] = {0, 250007, 500020, 750047,
                                           1000078, 1250115, 1500158, 1750207};

// ---------------- K1: gather emb rows -> A' in MFMA-fragment order ----------
// A'[mt][kt] is a 1KB block (mt=m/16, kt=k/32): byte lane*16 + j*2 holds
// A[mt*16 + (lane&15)][kt*32 + (lane>>4)*8 + j]  (16x16x32 A-frag layout).
// Block = one mt (16 rows x 8 heads). Thread t: m16=t&15, c=t>>4 (0..15):
// reads emb[rid(m,head=c>>1)] floats [(c&1)*64 .. +63] (256B contiguous),
// writes 8 x bf16x8; groups of 16 threads write 256B contiguous. Coalesced.
__global__ __launch_bounds__(256) void k_gather(const int* __restrict__ hidx,
                                                const float* __restrict__ emb,
                                                bf16* __restrict__ Ap) {
  const int t = threadIdx.x;
  const int m16 = t & 15, c = t >> 4;
  const int mbase = blockIdx.x * 16;
  const int head = c >> 1;
  const int rid = hidx[(mbase + m16) * 8 + head] + kHeadOff[head];
  const float* src = emb + (size_t)rid * 128 + (c & 1) * 64;
  char* dstbase = (char*)Ap + ((size_t)blockIdx.x * 32 + c * 2) * 1024;
#pragma unroll
  for (int j64 = 0; j64 < 2; ++j64) {
#pragma unroll
    for (int q = 0; q < 4; ++q) {
      const float4 v0 = *(const float4*)(src + j64 * 32 + q * 8);
      const float4 v1 = *(const float4*)(src + j64 * 32 + q * 8 + 4);
      bf16x8 o;
      o[0] = (bf16)v0.x; o[1] = (bf16)v0.y; o[2] = (bf16)v0.z; o[3] = (bf16)v0.w;
      o[4] = (bf16)v1.x; o[5] = (bf16)v1.y; o[6] = (bf16)v1.z; o[7] = (bf16)v1.w;
      *(bf16x8*)(dstbase + j64 * 1024 + (m16 + 16 * q) * 16) = o;
    }
  }
}

// ---------------- fp32 -> bf16 bulk convert (both weights, one launch) ------
__global__ __launch_bounds__(256) void k_cvt2(const float* __restrict__ s0,
                                              bf16* __restrict__ d0,
                                              const float* __restrict__ s1,
                                              bf16* __restrict__ d1) {
  int b = blockIdx.x;
  const float* src = s0;
  bf16* dst = d0;
  if (b >= 1280) { b -= 1280; src = s1; dst = d1; }
  const int i = (b * 256 + threadIdx.x) * 8;
  float4 a = *(const float4*)(src + i);
  float4 c = *(const float4*)(src + i + 4);
  bf16x8 o;
  o[0] = (bf16)a.x; o[1] = (bf16)a.y; o[2] = (bf16)a.z; o[3] = (bf16)a.w;
  o[4] = (bf16)c.x; o[5] = (bf16)c.y; o[6] = (bf16)c.z; o[7] = (bf16)c.w;
  *(bf16x8*)(dst + i) = o;
}

// reduce across the 16 lanes of each khalf group (lane = khalf*16 + r16)
__device__ __forceinline__ float red16(float v) {
  v += __shfl_xor(v, 1);
  v += __shfl_xor(v, 2);
  v += __shfl_xor(v, 4);
  v += __shfl_xor(v, 8);
  return v;
}

// ========== K2: 256x128-tile GEMM, A direct-from-global (fragment layout) ===
// C[m][n] = sum_k A[m][k] * W[n][k]; A' pre-fragmented, W=[2560][1024] row-maj.
// 512 thr = 8 waves (4M x 2N); per-wave out 64x64; acc[4][4] (64 VGPR).
// A-frags: coalesced 1KB global_load per (mi, phase), register-prefetched one
// phase ahead (aX/aY, unroll-2, static names). B via LDS: 2 buf x 8KB only.
// Phase p: {vmcnt(5) [stage(p) landed]; barrier; issue A(p+1)x4; 4 ds_read B;
// MFMA x16 (compiler fine-waits); lgkm0; barrier; stage B(p+2)}.
// Swizzle on B (64B rows): byte ^= ((row>>1)&3)<<4; source pre-swizzled.
// vt blocks: store Vt + S4 partials; kt: S1,S2,S3; LDS-reduced, 1 atomic each.

__global__ __launch_bounds__(512, 4) void k_gemm(const bf16* __restrict__ Af,
                                                 const bf16* __restrict__ Wv,
                                                 const bf16* __restrict__ Wk,
                                                 const float* __restrict__ hidden,
                                                 const float* __restrict__ g_h,
                                                 const float* __restrict__ g_k,
                                                 bf16* __restrict__ Vt,
                                                 float* __restrict__ S) {
  __shared__ __attribute__((aligned(16))) char ldsc[16384];  // 2 x 8KB B bufs
  const int tid = threadIdx.x;
  const int wid = tid >> 6, lane = tid & 63;
  const int wm = wid >> 1, wn = wid & 1;       // 4M x 2N
  const int r16 = lane & 15, khalf = lane >> 4;

  // XCD-aware bijective swizzle: 2560 = 8 xcd * 40 gx * 8 y
  const int w = blockIdx.x;
  const int xcd = w & 7;
  const int r_ = w >> 3;                       // 0..319
  const int gx = r_ >> 3;                      // 0..39 column block (slow)
  const int y = xcd * 8 + (r_ & 7);            // row panel (fast)
  const int m0 = y * 256;
  const bool isV = (gx < 20);
  const int n0 = (isV ? gx : gx - 20) * 128;
  const bf16* Wp = isV ? Wv : Wk;

  // A fragment base: mt = y*16 + wm*4 + mi, frag addr = (mt*32 + p)*1024
  const char* aF0 = (const char*)Af + ((size_t)(y * 16 + wm * 4) * 32) * 1024 +
                    lane * 16;
  // B read addressing (byte offsets into ldsc)
  const int sw = ((r16 >> 1) & 3) << 4;
  const int c0 = (khalf * 16) ^ sw;
  const int bRd = (wn * 64 + r16) * 64 + c0;   // + nj*1024 + buf

  // B staging source (pre-swizzled): unit = 8KB = 128 rows x 64B
  const int srow = tid >> 2;                   // 0..127
  const int scol = (((tid & 3) ^ ((tid >> 3) & 3))) * 8;
  const bf16* pB = Wp + (size_t)(n0 + srow) * EDIM + scol;

  f32x4 acc[4][4] = {};
  bf16x8 aX[4], aY[4], bF[4];

#define STAGEB(BUFO, KT) do {                                                  \
    __builtin_amdgcn_global_load_lds(AS1C(pB + (KT) * 32),                     \
        AS3(ldsc + (BUFO) + tid * 16), 16, 0, 0);                              \
    __builtin_amdgcn_sched_barrier(0);                                         \
  } while (0)

#define LOADA(DST, KT) do {                                                    \
    _Pragma("unroll") for (int mi = 0; mi < 4; ++mi)                           \
      DST[mi] = *(const bf16x8*)(aF0 + ((size_t)mi * 32 + (KT)) * 1024);       \
  } while (0)

#define PHASE(BUFO, ACUR, ANEXT, KT, LD_A, ST_B, VMC) do {                     \
    asm volatile("s_waitcnt vmcnt(" #VMC ")" ::: "memory");                    \
    __builtin_amdgcn_s_barrier();                                              \
    asm volatile("" ::: "memory");                                             \
    if (LD_A) LOADA(ANEXT, (KT) + 1);                                          \
    _Pragma("unroll") for (int nj = 0; nj < 4; ++nj)                           \
      bF[nj] = *(const bf16x8*)(ldsc + (BUFO) + bRd + nj * 1024);              \
    __builtin_amdgcn_s_setprio(1);                                             \
    _Pragma("unroll") for (int nj = 0; nj < 4; ++nj)                           \
      _Pragma("unroll") for (int mi = 0; mi < 4; ++mi)                         \
        acc[mi][nj] = __builtin_amdgcn_mfma_f32_16x16x32_bf16(                 \
            ACUR[mi], bF[nj], acc[mi][nj], 0, 0, 0);                           \
    __builtin_amdgcn_s_setprio(0);                                             \
    asm volatile("s_waitcnt lgkmcnt(0)" ::: "memory");                         \
    __builtin_amdgcn_s_barrier();                                              \
    if (ST_B) STAGEB(BUFO, (KT) + 2);                                          \
  } while (0)

  // prologue: stage B(0), B(1); load A(0)
  STAGEB(0, 0);
  STAGEB(8192, 1);
  LOADA(aX, 0);

  // steady state: phases 0..29 (stage up to tile 31)
  for (int p = 0; p < 30; p += 2) {
    PHASE(0, aX, aY, p, true, true, 5);
    PHASE(8192, aY, aX, p + 1, true, true, 5);
  }
  // tile 30: load A(31), no stage
  PHASE(0, aX, aY, 30, true, false, 5);
  // tile 31: drain
  PHASE(8192, aY, aX, 31, false, false, 4);

  // ---- epilogue: row = m0+wm*64+mi*16+khalf*4+r; col = n0+wn*64+nj*16+r16
  float* P = (float*)ldsc;
  if (isV) {
#pragma unroll
    for (int mi = 0; mi < 4; ++mi) {
#pragma unroll
      for (int nj = 0; nj < 4; ++nj) {
        const int col = n0 + wn * 64 + nj * 16 + r16;
#pragma unroll
        for (int r = 0; r < 4; ++r) {
          const int row = m0 + wm * 64 + mi * 16 + khalf * 4 + r;
          Vt[(size_t)row * HDIM + col] = (bf16)acc[mi][nj][r];
        }
      }
#pragma unroll
      for (int r = 0; r < 4; ++r) {
        float p = 0.f;
#pragma unroll
        for (int nj = 0; nj < 4; ++nj) p += acc[mi][nj][r] * acc[mi][nj][r];
        p = red16(p);
        if (r16 == 0) {
          const int rl = wm * 64 + mi * 16 + khalf * 4 + r;  // 0..255
          P[wn * 256 + rl] = p;
        }
      }
    }
    __syncthreads();
    if (tid < 256) {
      const float s = P[tid] + P[256 + tid];
      atomicAdd(&S[(size_t)(m0 + tid) * 4 + 3], s);
    }
  } else {
    float ghk[4];
#pragma unroll
    for (int nj = 0; nj < 4; ++nj) {
      const int col = n0 + wn * 64 + nj * 16 + r16;
      ghk[nj] = g_h[col] * g_k[col];
    }
#pragma unroll
    for (int mi = 0; mi < 4; ++mi) {
#pragma unroll
      for (int r = 0; r < 4; ++r) {
        const int row = m0 + wm * 64 + mi * 16 + khalf * 4 + r;
        float p1 = 0.f, p2 = 0.f, p3 = 0.f;
#pragma unroll
        for (int nj = 0; nj < 4; ++nj) {
          const int col = n0 + wn * 64 + nj * 16 + r16;
          const float k = acc[mi][nj][r];
          const float h = hidden[(size_t)row * HDIM + col];
          p1 += h * h;
          p2 += h * ghk[nj] * k;
          p3 += k * k;
        }
        p1 = red16(p1); p2 = red16(p2); p3 = red16(p3);
        if (r16 == 0) {
          const int rl = wm * 64 + mi * 16 + khalf * 4 + r;  // 0..255
          float* Pr = P + (wn * 256 + rl) * 3;
          Pr[0] = p1; Pr[1] = p2; Pr[2] = p3;
        }
      }
    }
    __syncthreads();
    for (int j = tid; j < 768; j += 512) {
      const int rl = j / 3, c = j % 3;
      const float s = P[j] + P[768 + j];
      atomicAdd(&S[(size_t)(m0 + rl) * 4 + c], s);
    }
  }
#undef STAGEB
#undef LOADA
#undef PHASE
}

// ---------------- K3: per-row scalars -> (alpha, alpha*inv_v) ----------------
__global__ __launch_bounds__(256) void k_scal(const float* __restrict__ S,
                                              float* __restrict__ AB) {
  const int m = blockIdx.x * 256 + threadIdx.x;
  const float s1 = S[(size_t)m * 4 + 0];
  const float s2 = S[(size_t)m * 4 + 1];
  const float s3 = S[(size_t)m * 4 + 2];
  const float s4 = S[(size_t)m * 4 + 3];
  const float inv_h = rsqrtf(s1 * (1.f / HDIM) + 1e-6f);
  const float inv_k = rsqrtf(s3 * (1.f / HDIM) + 1e-6f);
  const float dot = s2 * inv_h * inv_k * 0.019764235f;  // 1/sqrt(2560)
  float st = sqrtf(fmaxf(fabsf(dot), 1e-6f));
  st = (dot < 0.f) ? -st : st;
  if (dot == 0.f) st = 0.f;
  const float alpha = 1.f / (1.f + __expf(-st));
  const float inv_v = rsqrtf(alpha * alpha * s4 * (1.f / HDIM) + 1e-6f);
  AB[(size_t)m * 2 + 0] = alpha;
  AB[(size_t)m * 2 + 1] = alpha * inv_v;
}

// ---------------- K4: fused v_tilde/v_n recompute + conv + SiLU + residuals --
__global__ __launch_bounds__(320) void k_fuse(const float* __restrict__ hidden,
                                              const bf16* __restrict__ Vt,
                                              const float* __restrict__ AB,
                                              const float* __restrict__ g_v,
                                              const float* __restrict__ conv_w,
                                              const float* __restrict__ conv_b,
                                              float* __restrict__ out) {
  const int mbase = blockIdx.x * 8;
  const int l0 = mbase & (LSEQ - 1);
  const int t = threadIdx.x;
  const int h0 = t * 8;

  float gv[8], cb[8];
  *(float4*)&gv[0] = *(const float4*)(g_v + h0);
  *(float4*)&gv[4] = *(const float4*)(g_v + h0 + 4);
  *(float4*)&cb[0] = *(const float4*)(conv_b + h0);
  *(float4*)&cb[4] = *(const float4*)(conv_b + h0 + 4);
  float4 cw[8];
#pragma unroll
  for (int i = 0; i < 8; ++i)
    cw[i] = *(const float4*)(conv_w + (size_t)(h0 + i) * 4);

  float win[4][8];
#pragma unroll
  for (int jj = 0; jj < 4; ++jj)
#pragma unroll
    for (int i = 0; i < 8; ++i) win[jj][i] = 0.f;

#pragma unroll
  for (int j = 0; j < 11; ++j) {  // source rows mbase-3 .. mbase+7
    const int lj = l0 - 3 + j;
    const int m = mbase - 3 + j;
    float vtl[8];
    if (lj >= 0) {
      const float alpha = AB[(size_t)m * 2 + 0];
      const float av = AB[(size_t)m * 2 + 1];
      const bf16x8 v = *(const bf16x8*)(Vt + (size_t)m * HDIM + h0);
#pragma unroll
      for (int i = 0; i < 8; ++i) {
        const float vt = (float)v[i];
        vtl[i] = alpha * vt;
        win[j & 3][i] = av * vt * gv[i];  // v_n
      }
    } else {
#pragma unroll
      for (int i = 0; i < 8; ++i) { win[j & 3][i] = 0.f; vtl[i] = 0.f; }
    }
    if (j >= 3) {
      const int R = mbase + j - 3;
      const size_t base = (size_t)R * HDIM + h0;
      float hx[8];
      *(float4*)&hx[0] = *(const float4*)(hidden + base);
      *(float4*)&hx[4] = *(const float4*)(hidden + base + 4);
      float o[8];
#pragma unroll
      for (int i = 0; i < 8; ++i) {
        float c = cb[i];
        c += ((const float*)&cw[i])[0] * win[(j - 3) & 3][i];
        c += ((const float*)&cw[i])[1] * win[(j - 2) & 3][i];
        c += ((const float*)&cw[i])[2] * win[(j - 1) & 3][i];
        c += ((const float*)&cw[i])[3] * win[j & 3][i];
        const float y = c / (1.f + __expf(-c));  // silu
        o[i] = hx[i] + y + vtl[i];
      }
      *(float4*)(out + base) = *(float4*)&o[0];
      *(float4*)(out + base + 4) = *(float4*)&o[4];
    }
  }
}

// ---------------- launcher ----------------
extern "C" void kernel_launch(void* const* d_in, const int* in_sizes, int n_in,
                              void* d_out, int out_size, void* d_ws,
                              size_t ws_size, hipStream_t stream) {
  const float* hidden = (const float*)d_in[0];
  const int* hashidx = (const int*)d_in[1];
  const float* emb = (const float*)d_in[2];
  const float* w_v = (const float*)d_in[3];
  const float* w_k = (const float*)d_in[4];
  const float* g_h = (const float*)d_in[5];
  const float* g_k = (const float*)d_in[6];
  const float* g_v = (const float*)d_in[7];
  const float* conv_w = (const float*)d_in[8];
  const float* conv_b = (const float*)d_in[9];
  float* out = (float*)d_out;

  char* w = (char*)d_ws;
  bf16* a16 = (bf16*)w;  w += (size_t)MROWS * EDIM * 2;   // 33.5 MB (A' frags)
  bf16* wv16 = (bf16*)w; w += (size_t)HDIM * EDIM * 2;    // 5.2 MB
  bf16* wk16 = (bf16*)w; w += (size_t)HDIM * EDIM * 2;    // 5.2 MB
  bf16* vt16 = (bf16*)w; w += (size_t)MROWS * HDIM * 2;   // 83.9 MB
  float* S = (float*)w;  w += (size_t)MROWS * 4 * 4;      // 256 KB
  float* AB = (float*)w; w += (size_t)MROWS * 2 * 4;      // 128 KB

  hipMemsetAsync(S, 0, (size_t)MROWS * 4 * 4, stream);
  k_gather<<<MROWS / 16, 256, 0, stream>>>(hashidx, emb, a16);
  k_cvt2<<<2560, 256, 0, stream>>>(w_v, wv16, w_k, wk16);
  k_gemm<<<dim3(2560), 512, 0, stream>>>(a16, wv16, wk16, hidden, g_h, g_k,
                                         vt16, S);
  k_scal<<<MROWS / 256, 256, 0, stream>>>(S, AB);
  k_fuse<<<MROWS / 8, 320, 0, stream>>>(hidden, vt16, AB, g_v, conv_w, conv_b,
                                        out);
}

// Round 8
// 329.657 us; speedup vs baseline: 1.0186x; 1.0186x over previous
//
#include <hip/hip_runtime.h>
#include <cstddef>
#include <cstdint>

typedef __bf16 bf16;
typedef __bf16 bf16x4 __attribute__((ext_vector_type(4)));
typedef __bf16 bf16x8 __attribute__((ext_vector_type(8)));
typedef float f32x4 __attribute__((ext_vector_type(4)));

#define AS1C(p) ((const __attribute__((address_space(1))) void*)(p))
#define AS3(p)  ((__attribute__((address_space(3))) void*)(p))

#define MROWS 16384
#define HDIM 2560
#define EDIM 1024
#define LSEQ 4096

static __device__ const int kHeadOff[8] = {0, 250007, 500020, 750047,
                                           1000078, 1250115, 1500158, 1750207};

// ---------------- K1: gather emb rows -> bf16 E [MROWS][1024] ----------------
// 2 rows/block; per lane: 32B read, 16B coalesced write.  (R6 version)
__global__ __launch_bounds__(256) void k_gather(const int* __restrict__ hidx,
                                                const float* __restrict__ emb,
                                                bf16* __restrict__ E) {
  const int t = threadIdx.x;
  const int m = blockIdx.x * 2 + (t >> 7);
  const int tt = t & 127;
  const int head = tt >> 4;         // 8 heads x 16 lanes
  const int e8 = (tt & 15) * 8;     // 8 floats per lane
  const int rid = hidx[m * 8 + head] + kHeadOff[head];
  const float4 v0 = *(const float4*)(emb + (size_t)rid * 128 + e8);
  const float4 v1 = *(const float4*)(emb + (size_t)rid * 128 + e8 + 4);
  bf16x8 o;
  o[0] = (bf16)v0.x; o[1] = (bf16)v0.y; o[2] = (bf16)v0.z; o[3] = (bf16)v0.w;
  o[4] = (bf16)v1.x; o[5] = (bf16)v1.y; o[6] = (bf16)v1.z; o[7] = (bf16)v1.w;
  *(bf16x8*)(E + (size_t)m * EDIM + head * 128 + e8) = o;
}

// ---------------- fp32 -> bf16 bulk convert (both weights, one launch) ------
__global__ __launch_bounds__(256) void k_cvt2(const float* __restrict__ s0,
                                              bf16* __restrict__ d0,
                                              const float* __restrict__ s1,
                                              bf16* __restrict__ d1) {
  int b = blockIdx.x;
  const float* src = s0;
  bf16* dst = d0;
  if (b >= 1280) { b -= 1280; src = s1; dst = d1; }
  const int i = (b * 256 + threadIdx.x) * 8;
  float4 a = *(const float4*)(src + i);
  float4 c = *(const float4*)(src + i + 4);
  bf16x8 o;
  o[0] = (bf16)a.x; o[1] = (bf16)a.y; o[2] = (bf16)a.z; o[3] = (bf16)a.w;
  o[4] = (bf16)c.x; o[5] = (bf16)c.y; o[6] = (bf16)c.z; o[7] = (bf16)c.w;
  *(bf16x8*)(dst + i) = o;
}

// reduce across the 16 lanes of each khalf group (lane = khalf*16 + r16)
__device__ __forceinline__ float red16(float v) {
  v += __shfl_xor(v, 1);
  v += __shfl_xor(v, 2);
  v += __shfl_xor(v, 4);
  v += __shfl_xor(v, 8);
  return v;
}

// ========= K2: 256x128-tile GEMM, BK=32, 3-buffer single-barrier pipe =======
// C[m][n] = sum_k A[m][k] * W[n][k];  A=[16384][1024], W=[2560][1024]
// 512 thr = 8 waves (4M x 2N); per-wave out 64x64; acc[4][4] (64 VGPR).
// LDS 72KB: 3 buf x (A [256][32] 16KB + B [128][32] 8KB) -> 2 blocks/CU.
// Phase p: {STAGE(p+2) -> buf[(p+2)%3] (dest drained at end of p-1);
//   8 ds_read from buf[p%3]; 16 MFMA (compiler fine-waits);
//   s_waitcnt lgkmcnt(0) vmcnt(3); barrier}.   ONE barrier per phase,
// 2-phase stage latency, counted vmcnt (6 outstanding, wait 3).
// Swizzle (64B rows): byte ^= ((row>>1)&3)<<4 (2-way alias free, m136);
// staging source pre-swizzled with same involution, LDS dest linear.
// vt blocks: store Vt bf16 + S4 partials; kt: no store, S1,S2,S3 partials;
// partials LDS-reduced across wn -> 1 atomic per (row,comp) per block.

#define LDSB 24576  // bytes per buffer: A 16384 + B 8192

__global__ __launch_bounds__(512, 4) void k_gemm(const bf16* __restrict__ A,
                                                 const bf16* __restrict__ Wv,
                                                 const bf16* __restrict__ Wk,
                                                 const float* __restrict__ hidden,
                                                 const float* __restrict__ g_h,
                                                 const float* __restrict__ g_k,
                                                 bf16* __restrict__ Vt,
                                                 float* __restrict__ S) {
  __shared__ __attribute__((aligned(16))) char ldsc[3 * LDSB];
  const int tid = threadIdx.x;
  const int wid = tid >> 6, lane = tid & 63;
  const int wm = wid >> 1, wn = wid & 1;       // 4M x 2N
  const int r16 = lane & 15, khalf = lane >> 4;

  // XCD-aware bijective swizzle: 2560 = 8 xcd * 40 gx * 8 y
  const int w = blockIdx.x;
  const int xcd = w & 7;
  const int r_ = w >> 3;                       // 0..319
  const int gx = r_ >> 3;                      // 0..39 column block (slow)
  const int y = xcd * 8 + (r_ & 7);            // row panel (fast)
  const int m0 = y * 256;
  const bool isV = (gx < 20);
  const int n0 = (isV ? gx : gx - 20) * 128;
  const bf16* Wp = isV ? Wv : Wk;

  // read addressing (byte offsets into ldsc)
  const int sw = ((r16 >> 1) & 3) << 4;        // row-derived swizzle
  const int c0 = (khalf * 16) ^ sw;
  const int aRd = (wm * 64 + r16) * 64 + c0;             // + mi*1024 + buf
  const int bRd = 16384 + (wn * 64 + r16) * 64 + c0;     // + nj*1024 + buf

  // staging source (pre-swizzled): unit = 8KB = 128 rows x 64B
  const int srow = tid >> 2;                   // 0..127 row within unit
  const int scol = (((tid & 3) ^ ((tid >> 3) & 3))) * 8; // element offset
  const bf16* pA0 = A + (size_t)(m0 + srow) * EDIM + scol;
  const bf16* pA1 = pA0 + (size_t)128 * EDIM;
  const bf16* pB = Wp + (size_t)(n0 + srow) * EDIM + scol;
  const int ldsW = wid * 1024;                 // wave slice within unit

  f32x4 acc[4][4] = {};

#define STAGE(BUFO, KT) do {                                                   \
    __builtin_amdgcn_global_load_lds(AS1C(pA0 + (KT) * 32),                    \
        AS3(ldsc + (BUFO) + ldsW), 16, 0, 0);                                  \
    __builtin_amdgcn_global_load_lds(AS1C(pA1 + (KT) * 32),                    \
        AS3(ldsc + (BUFO) + 8192 + ldsW), 16, 0, 0);                           \
    __builtin_amdgcn_global_load_lds(AS1C(pB + (KT) * 32),                     \
        AS3(ldsc + (BUFO) + 16384 + ldsW), 16, 0, 0);                          \
    __builtin_amdgcn_sched_barrier(0);                                         \
  } while (0)

  // VMC: -1 = no vmcnt (tail), else s_waitcnt vmcnt(VMC) combined with lgkm0.
#define PHASE(BUFO, STBUF, KT, ST, VMW) do {                                   \
    if (ST) STAGE(STBUF, (KT) + 2);                                            \
    bf16x8 aF[4], bF[4];                                                       \
    _Pragma("unroll") for (int mi = 0; mi < 4; ++mi)                           \
      aF[mi] = *(const bf16x8*)(ldsc + (BUFO) + aRd + mi * 1024);              \
    _Pragma("unroll") for (int nj = 0; nj < 4; ++nj)                           \
      bF[nj] = *(const bf16x8*)(ldsc + (BUFO) + bRd + nj * 1024);              \
    __builtin_amdgcn_s_setprio(1);                                             \
    _Pragma("unroll") for (int nj = 0; nj < 4; ++nj)                           \
      _Pragma("unroll") for (int mi = 0; mi < 4; ++mi)                         \
        acc[mi][nj] = __builtin_amdgcn_mfma_f32_16x16x32_bf16(                 \
            aF[mi], bF[nj], acc[mi][nj], 0, 0, 0);                             \
    __builtin_amdgcn_s_setprio(0);                                             \
    asm volatile("s_waitcnt " VMW " lgkmcnt(0)" ::: "memory");                 \
    __builtin_amdgcn_s_barrier();                                              \
  } while (0)

  // prologue: stage tiles 0,1 into buf0,buf1; wait tile0 landed
  STAGE(0, 0);
  STAGE(LDSB, 1);
  asm volatile("s_waitcnt vmcnt(3)" ::: "memory");
  __builtin_amdgcn_s_barrier();

  // steady state: tiles 0..29 (stage tiles 2..31, two phases ahead)
  for (int p = 0; p < 30; p += 3) {
    PHASE(0,        2 * LDSB, p,     true, "vmcnt(3)");
    PHASE(LDSB,     0,        p + 1, true, "vmcnt(3)");
    PHASE(2 * LDSB, LDSB,     p + 2, true, "vmcnt(3)");
  }
  // tile 30 (buf0): no stage; drain stage(31)
  PHASE(0, 0, 30, false, "vmcnt(0)");
  // tile 31 (buf1): no stage, nothing outstanding
  PHASE(LDSB, 0, 31, false, "");

  // ---- epilogue: row = m0+wm*64+mi*16+khalf*4+r; col = n0+wn*64+nj*16+r16
  float* P = (float*)ldsc;  // free after final barrier (all reads drained)
  if (isV) {
#pragma unroll
    for (int mi = 0; mi < 4; ++mi) {
#pragma unroll
      for (int nj = 0; nj < 4; ++nj) {
        const int col = n0 + wn * 64 + nj * 16 + r16;
#pragma unroll
        for (int r = 0; r < 4; ++r) {
          const int row = m0 + wm * 64 + mi * 16 + khalf * 4 + r;
          Vt[(size_t)row * HDIM + col] = (bf16)acc[mi][nj][r];
        }
      }
#pragma unroll
      for (int r = 0; r < 4; ++r) {
        float p = 0.f;
#pragma unroll
        for (int nj = 0; nj < 4; ++nj) p += acc[mi][nj][r] * acc[mi][nj][r];
        p = red16(p);
        if (r16 == 0) {
          const int rl = wm * 64 + mi * 16 + khalf * 4 + r;  // 0..255
          P[wn * 256 + rl] = p;
        }
      }
    }
    __syncthreads();
    if (tid < 256) {
      const float s = P[tid] + P[256 + tid];
      atomicAdd(&S[(size_t)(m0 + tid) * 4 + 3], s);
    }
  } else {
    float ghk[4];
#pragma unroll
    for (int nj = 0; nj < 4; ++nj) {
      const int col = n0 + wn * 64 + nj * 16 + r16;
      ghk[nj] = g_h[col] * g_k[col];
    }
#pragma unroll
    for (int mi = 0; mi < 4; ++mi) {
#pragma unroll
      for (int r = 0; r < 4; ++r) {
        const int row = m0 + wm * 64 + mi * 16 + khalf * 4 + r;
        float p1 = 0.f, p2 = 0.f, p3 = 0.f;
#pragma unroll
        for (int nj = 0; nj < 4; ++nj) {
          const int col = n0 + wn * 64 + nj * 16 + r16;
          const float k = acc[mi][nj][r];
          const float h = hidden[(size_t)row * HDIM + col];
          p1 += h * h;
          p2 += h * ghk[nj] * k;
          p3 += k * k;
        }
        p1 = red16(p1); p2 = red16(p2); p3 = red16(p3);
        if (r16 == 0) {
          const int rl = wm * 64 + mi * 16 + khalf * 4 + r;  // 0..255
          float* Pr = P + (wn * 256 + rl) * 3;
          Pr[0] = p1; Pr[1] = p2; Pr[2] = p3;
        }
      }
    }
    __syncthreads();
    for (int j = tid; j < 768; j += 512) {
      const int rl = j / 3, c = j % 3;
      const float s = P[j] + P[768 + j];
      atomicAdd(&S[(size_t)(m0 + rl) * 4 + c], s);
    }
  }
#undef STAGE
#undef PHASE
}

// ---- per-row scalars from S (inlined into k_fuse; k_scal kernel removed) ---
__device__ __forceinline__ void row_scal(const float* __restrict__ S, int m,
                                         float& alpha, float& av) {
  const float4 s = *(const float4*)(S + (size_t)m * 4);
  const float inv_h = rsqrtf(s.x * (1.f / HDIM) + 1e-6f);
  const float inv_k = rsqrtf(s.z * (1.f / HDIM) + 1e-6f);
  const float dot = s.y * inv_h * inv_k * 0.019764235f;  // 1/sqrt(2560)
  float st = sqrtf(fmaxf(fabsf(dot), 1e-6f));
  st = (dot < 0.f) ? -st : st;
  if (dot == 0.f) st = 0.f;
  alpha = 1.f / (1.f + __expf(-st));
  av = alpha * rsqrtf(alpha * alpha * s.w * (1.f / HDIM) + 1e-6f);
}

// ---------------- K4: fused v_tilde/v_n recompute + conv + SiLU + residuals --
__global__ __launch_bounds__(320) void k_fuse(const float* __restrict__ hidden,
                                              const bf16* __restrict__ Vt,
                                              const float* __restrict__ S,
                                              const float* __restrict__ g_v,
                                              const float* __restrict__ conv_w,
                                              const float* __restrict__ conv_b,
                                              float* __restrict__ out) {
  const int mbase = blockIdx.x * 8;
  const int l0 = mbase & (LSEQ - 1);
  const int t = threadIdx.x;
  const int h0 = t * 8;

  float gv[8], cb[8];
  *(float4*)&gv[0] = *(const float4*)(g_v + h0);
  *(float4*)&gv[4] = *(const float4*)(g_v + h0 + 4);
  *(float4*)&cb[0] = *(const float4*)(conv_b + h0);
  *(float4*)&cb[4] = *(const float4*)(conv_b + h0 + 4);
  float4 cw[8];
#pragma unroll
  for (int i = 0; i < 8; ++i)
    cw[i] = *(const float4*)(conv_w + (size_t)(h0 + i) * 4);

  float win[4][8];
#pragma unroll
  for (int jj = 0; jj < 4; ++jj)
#pragma unroll
    for (int i = 0; i < 8; ++i) win[jj][i] = 0.f;

#pragma unroll
  for (int j = 0; j < 11; ++j) {  // source rows mbase-3 .. mbase+7
    const int lj = l0 - 3 + j;
    const int m = mbase - 3 + j;
    float vtl[8];
    if (lj >= 0) {
      float alpha, av;
      row_scal(S, m, alpha, av);
      const bf16x8 v = *(const bf16x8*)(Vt + (size_t)m * HDIM + h0);
#pragma unroll
      for (int i = 0; i < 8; ++i) {
        const float vt = (float)v[i];
        vtl[i] = alpha * vt;
        win[j & 3][i] = av * vt * gv[i];  // v_n
      }
    } else {
#pragma unroll
      for (int i = 0; i < 8; ++i) { win[j & 3][i] = 0.f; vtl[i] = 0.f; }
    }
    if (j >= 3) {
      const int R = mbase + j - 3;
      const size_t base = (size_t)R * HDIM + h0;
      float hx[8];
      *(float4*)&hx[0] = *(const float4*)(hidden + base);
      *(float4*)&hx[4] = *(const float4*)(hidden + base + 4);
      float o[8];
#pragma unroll
      for (int i = 0; i < 8; ++i) {
        float c = cb[i];
        c += ((const float*)&cw[i])[0] * win[(j - 3) & 3][i];
        c += ((const float*)&cw[i])[1] * win[(j - 2) & 3][i];
        c += ((const float*)&cw[i])[2] * win[(j - 1) & 3][i];
        c += ((const float*)&cw[i])[3] * win[j & 3][i];
        const float y = c / (1.f + __expf(-c));  // silu
        o[i] = hx[i] + y + vtl[i];
      }
      *(float4*)(out + base) = *(float4*)&o[0];
      *(float4*)(out + base + 4) = *(float4*)&o[4];
    }
  }
}

// ---------------- launcher ----------------
extern "C" void kernel_launch(void* const* d_in, const int* in_sizes, int n_in,
                              void* d_out, int out_size, void* d_ws,
                              size_t ws_size, hipStream_t stream) {
  const float* hidden = (const float*)d_in[0];
  const int* hashidx = (const int*)d_in[1];
  const float* emb = (const float*)d_in[2];
  const float* w_v = (const float*)d_in[3];
  const float* w_k = (const float*)d_in[4];
  const float* g_h = (const float*)d_in[5];
  const float* g_k = (const float*)d_in[6];
  const float* g_v = (const float*)d_in[7];
  const float* conv_w = (const float*)d_in[8];
  const float* conv_b = (const float*)d_in[9];
  float* out = (float*)d_out;

  char* w = (char*)d_ws;
  bf16* e16 = (bf16*)w;  w += (size_t)MROWS * EDIM * 2;   // 33.5 MB
  bf16* wv16 = (bf16*)w; w += (size_t)HDIM * EDIM * 2;    // 5.2 MB
  bf16* wk16 = (bf16*)w; w += (size_t)HDIM * EDIM * 2;    // 5.2 MB
  bf16* vt16 = (bf16*)w; w += (size_t)MROWS * HDIM * 2;   // 83.9 MB
  float* S = (float*)w;  w += (size_t)MROWS * 4 * 4;      // 256 KB

  hipMemsetAsync(S, 0, (size_t)MROWS * 4 * 4, stream);
  k_gather<<<MROWS / 2, 256, 0, stream>>>(hashidx, emb, e16);
  k_cvt2<<<2560, 256, 0, stream>>>(w_v, wv16, w_k, wk16);
  k_gemm<<<dim3(2560), 512, 0, stream>>>(e16, wv16, wk16, hidden, g_h, g_k,
                                         vt16, S);
  k_fuse<<<MROWS / 8, 320, 0, stream>>>(hidden, vt16, S, g_v, conv_w, conv_b,
                                        out);
}